// Round 8
// baseline (287.948 us; speedup 1.0000x reference)
//
#include <hip/hip_runtime.h>
#include <hip/hip_bf16.h>

// B=4, S=2048, E=1024, H=16, D=64, WIN=512.
// out = ( swa_alibi( split_heads(x @ w_in^T) ) merged ) @ w_out^T
//
// k1: gemm_bt writes Q,K -> qk[8192][2048]; V transposed -> vT[b][h][64][2048]
// k2: attn reads qk + vT (V already transposed: b128 staging, no LDS scatter)
// k3: gemm_bt o @ w_out^T -> out

typedef __bf16 bf16x8 __attribute__((ext_vector_type(8)));
typedef float f32x4 __attribute__((ext_vector_type(4)));

__device__ __forceinline__ f32x4 mfma16(bf16x8 a, bf16x8 b, f32x4 c) {
    return __builtin_amdgcn_mfma_f32_16x16x32_bf16(a, b, c, 0, 0, 0);
}

__device__ __forceinline__ void gload_lds16(const void* g, void* l) {
    __builtin_amdgcn_global_load_lds(
        (const __attribute__((address_space(1))) unsigned int*)(unsigned long long)g,
        (__attribute__((address_space(3))) unsigned int*)(unsigned int)(unsigned long long)l,
        16, 0, 0);
}

__device__ __forceinline__ unsigned pkbf(float a, float b) {
    unsigned short ua = __builtin_bit_cast(unsigned short, (__bf16)a);
    unsigned short ub = __builtin_bit_cast(unsigned short, (__bf16)b);
    return (unsigned)ua | ((unsigned)ub << 16);
}

__global__ void init_flag(int* flag) { *flag = 0; }

// f32 data read as bf16 halfwords shows huge exponents (p~0.45 per halfword).
__global__ void detect_f32(const unsigned short* __restrict__ w, int n, int* flag) {
    int i = blockIdx.x * blockDim.x + threadIdx.x;
    int hit = 0;
    for (; i < n; i += gridDim.x * blockDim.x) {
        int e = (w[i] >> 7) & 0xFF;
        if (e >= 0x8D) hit = 1;
    }
    unsigned long long m = __ballot(hit);
    if (m != 0 && (threadIdx.x & 63) == 0) atomicOr(flag, 1);
}

// Converts all three inputs f32->bf16 iff flag set; else no-op.
__global__ void cvt_all(const void* __restrict__ x, const void* __restrict__ wi,
                        const void* __restrict__ wo, __bf16* __restrict__ xb,
                        __bf16* __restrict__ wib, __bf16* __restrict__ wob,
                        const int* __restrict__ flag) {
    if (*flag == 0) return;
    const int XN = 8192 * 1024, WI = 3072 * 1024, WO = 1024 * 1024;
    const int stride = gridDim.x * blockDim.x;
    int i0 = blockIdx.x * blockDim.x + threadIdx.x;
    for (int j = i0; j < XN; j += stride) xb[j] = (__bf16)((const float*)x)[j];
    for (int j = i0; j < WI; j += stride) wib[j] = (__bf16)((const float*)wi)[j];
    for (int j = i0; j < WO; j += stride) wob[j] = (__bf16)((const float*)wo)[j];
}

// C = A[M,K] @ Bt[N,K]^T. 128x128 tile, BK=64, global_load_lds staging with
// XOR-chunk lane mapping (lane's GLOBAL chunk permuted so the fixed lane*16
// LDS layout lands swizzled -> conflict-free pitch-64 b128 reads).
// Column blocks with n0>=2048 (gemm1's V part) store TRANSPOSED to vTp
// [b][h][d][s]; other blocks store to Cb (pitch ldc) or Cf (f32 out).
__global__ __launch_bounds__(256, 3) void gemm_bt(
        const void* __restrict__ Araw, const __bf16* __restrict__ Acvt,
        const void* __restrict__ Braw, const __bf16* __restrict__ Bcvt,
        __bf16* __restrict__ Cb, float* __restrict__ Cf,
        __bf16* __restrict__ vTp, const int* __restrict__ flagp,
        int M, int N, int K, int ldc) {
    __shared__ __align__(16) __bf16 As[128 * 64];
    __shared__ __align__(16) __bf16 Bs[128 * 64];

    const int t = threadIdx.x;
    const int lane = t & 63;
    const int w = t >> 6;
    const int wr = w >> 1, wc = w & 1;
    const int q4 = lane >> 4, l16 = lane & 15;
    const int m0 = blockIdx.y * 128, n0 = blockIdx.x * 128;
    const bool isf32 = (*flagp != 0);
    const __bf16* A = isf32 ? Acvt : (const __bf16*)Araw;
    const __bf16* Bt = isf32 ? Bcvt : (const __bf16*)Braw;

    f32x4 acc[4][4] = {};

    const int lr = lane >> 3;
    const int lc = (lane & 7) ^ lr;  // global chunk -> LDS slot swizzle

    for (int k0 = 0; k0 < K; k0 += 64) {
#pragma unroll
        for (int p = 0; p < 4; ++p) {
            int r0 = w * 32 + p * 8;
            gload_lds16(&A[(size_t)(m0 + r0 + lr) * K + k0 + lc * 8], &As[r0 * 64]);
            gload_lds16(&Bt[(size_t)(n0 + r0 + lr) * K + k0 + lc * 8], &Bs[r0 * 64]);
        }
        __syncthreads();

#pragma unroll
        for (int kt = 0; kt < 2; ++kt) {
            bf16x8 af[4], bfr[4];
#pragma unroll
            for (int mt = 0; mt < 4; ++mt) {
                int row = wr * 64 + mt * 16 + l16;
                af[mt] = *(const bf16x8*)&As[row * 64 + (((kt * 4 + q4) ^ (row & 7)) << 3)];
            }
#pragma unroll
            for (int nt = 0; nt < 4; ++nt) {
                int row = wc * 64 + nt * 16 + l16;
                bfr[nt] = *(const bf16x8*)&Bs[row * 64 + (((kt * 4 + q4) ^ (row & 7)) << 3)];
            }
#pragma unroll
            for (int mt = 0; mt < 4; ++mt)
#pragma unroll
                for (int nt = 0; nt < 4; ++nt)
                    acc[mt][nt] = mfma16(af[mt], bfr[nt], acc[mt][nt]);
        }
        __syncthreads();
    }

    // C/D layout: col=lane&15, row=(lane>>4)*4+reg
    if (vTp && n0 >= 2048) {
        // V part -> vT[b][h][d][s], packed 4 consecutive s per uint2
        const int b = m0 >> 11;
        const int s0 = (m0 & 2047) + wr * 64 + q4 * 4;
#pragma unroll
        for (int mt = 0; mt < 4; ++mt)
#pragma unroll
            for (int nt = 0; nt < 4; ++nt) {
                int dg = n0 - 2048 + wc * 64 + nt * 16 + l16;
                size_t base = ((size_t)(b * 16 + (dg >> 6)) * 64 + (dg & 63)) * 2048 +
                              s0 + mt * 16;
                uint2 pk;
                pk.x = pkbf(acc[mt][nt][0], acc[mt][nt][1]);
                pk.y = pkbf(acc[mt][nt][2], acc[mt][nt][3]);
                *(uint2*)&vTp[base] = pk;
            }
    } else {
#pragma unroll
        for (int mt = 0; mt < 4; ++mt)
#pragma unroll
            for (int nt = 0; nt < 4; ++nt) {
                int col = n0 + wc * 64 + nt * 16 + l16;
#pragma unroll
                for (int r = 0; r < 4; ++r) {
                    int row = m0 + wr * 64 + mt * 16 + q4 * 4 + r;
                    if (Cf && isf32)
                        Cf[(size_t)row * ldc + col] = acc[mt][nt][r];
                    else
                        Cb[(size_t)row * ldc + col] = (__bf16)acc[mt][nt][r];
                }
            }
    }
}

// Sliding-window causal attention + ALiBi, flash-style, S^T orientation,
// 64-key sub-iterations, register-prefetched K/V staging (V pre-transposed
// by gemm1 -> pure b128 vector staging, no LDS scatter), swizzled LDS.
// grid = (S/128, H, B) with qt reversed (heavy blocks first).
__global__ __launch_bounds__(256, 2) void attn(
        const __bf16* __restrict__ qk, const __bf16* __restrict__ vT,
        __bf16* __restrict__ o) {
    // Ks : 128 keys x 64 d, pitch 64, chunk-swizzled   [0, 16384)
    // VTs: 64 d x 128 keys, pitch 128, chunk-swizzled  [16384, 32768)
    // Ps : 128 q x 64 keys, pitch 72                   [32768, 51200)
    // Ot : epilogue transpose buffer, aliases Ks
    __shared__ __align__(16) char smem[51200];
    __bf16* Ks  = (__bf16*)smem;
    __bf16* VTs = (__bf16*)(smem + 16384);
    __bf16* Ps  = (__bf16*)(smem + 32768);
    __bf16* Ot  = (__bf16*)smem;

    const int qt = 15 - blockIdx.x, h = blockIdx.y, b = blockIdx.z;
    const int t = threadIdx.x;
    const int lane = t & 63, w = t >> 6;
    const int q4 = lane >> 4, l16 = lane & 15;
    const int q0 = qt * 128, qw0 = q0 + w * 32;

    const float L2E = 1.4426950408889634f;
    const float slope2 = exp2f(-(float)(h + 1) * 0.5f) * L2E;  // alibi slope * log2e
    const float scale2 = L2E * 0.125f;                         // log2e / sqrt(64)

    // K staging coords: thread covers rows (p*32+srow), chunk scb (swizzled commit)
    const int srow = t >> 3, scb = t & 7;
    const int ksoff = (scb ^ (srow & 7)) << 3;
    // V staging coords: thread covers d-row (w*16+p*4+vr), slot vs
    const int vr = lane >> 4, vs = lane & 15;

    // Q as B-operand (lane l16 = query, k = d), straight b128 from qk
    bf16x8 qf[2][2];
    const size_t qbase = ((size_t)b * 2048 + q0) * 2048 + (size_t)h * 64;
#pragma unroll
    for (int nt = 0; nt < 2; ++nt)
#pragma unroll
        for (int kt = 0; kt < 2; ++kt)
            qf[nt][kt] = *(const bf16x8*)&qk[qbase +
                (size_t)(w * 32 + nt * 16 + l16) * 2048 + kt * 32 + q4 * 8];

    f32x4 O[4][2] = {};  // O^T: [d-tile][q-tile], col l16=q, row q4*4+r=d
    float mrow[2] = {-1e30f, -1e30f}, lrow[2] = {0.0f, 0.0f};

    const int nkt = (qt < 4 ? qt : 4) + 1;
    const int ktile0 = qt - (nkt - 1);
    const size_t kbh = (size_t)b * 2048 * 2048 + 1024 + (size_t)h * 64;
    const size_t vbh = (size_t)(b * 16 + h) * 64 * 2048;

    uint4 kpre[4], vpre[4];

    // prologue: load + commit tile 0
    {
        const size_t kb = kbh + (size_t)(ktile0 * 128) * 2048;
        const int vk0 = ktile0 * 128;
#pragma unroll
        for (int p = 0; p < 4; ++p)
            kpre[p] = *(const uint4*)&qk[kb + (size_t)(p * 32 + srow) * 2048 + scb * 8];
#pragma unroll
        for (int p = 0; p < 4; ++p) {
            int d = w * 16 + p * 4 + vr;
            int g = (vs & 8) | ((vs & 7) ^ (d & 7));
            vpre[p] = *(const uint4*)&vT[vbh + (size_t)d * 2048 + vk0 + g * 8];
        }
#pragma unroll
        for (int p = 0; p < 4; ++p) {
            *(uint4*)&Ks[(p * 32 + srow) * 64 + ksoff] = kpre[p];
            int d = w * 16 + p * 4 + vr;
            *(uint4*)&VTs[d * 128 + vs * 8] = vpre[p];
        }
    }
    __syncthreads();

    for (int ki = 0; ki < nkt; ++ki) {
        const int k0 = (ktile0 + ki) * 128;
        if (ki + 1 < nkt) {  // issue next tile's loads (no wait)
            const size_t kb = kbh + (size_t)(k0 + 128) * 2048;
#pragma unroll
            for (int p = 0; p < 4; ++p)
                kpre[p] = *(const uint4*)&qk[kb + (size_t)(p * 32 + srow) * 2048 + scb * 8];
#pragma unroll
            for (int p = 0; p < 4; ++p) {
                int d = w * 16 + p * 4 + vr;
                int g = (vs & 8) | ((vs & 7) ^ (d & 7));
                vpre[p] = *(const uint4*)&vT[vbh + (size_t)d * 2048 + k0 + 128 + g * 8];
            }
        }

#pragma unroll 1
        for (int hh = 0; hh < 2; ++hh) {
            const int ks0 = k0 + hh * 64;
            if (qw0 + 31 < ks0 || qw0 - 512 > ks0 + 63) continue;  // wave-uniform skip

            // S^T = K·Q^T over this 64-key subtile
            f32x4 sc[2][4] = {};
#pragma unroll
            for (int mt = 0; mt < 4; ++mt) {
                int krow = hh * 64 + mt * 16 + l16;
                bf16x8 ak0 = *(const bf16x8*)&Ks[krow * 64 + ((q4 ^ (l16 & 7)) << 3)];
                bf16x8 ak1 = *(const bf16x8*)&Ks[krow * 64 + (((4 + q4) ^ (l16 & 7)) << 3)];
                sc[0][mt] = mfma16(ak0, qf[0][0], sc[0][mt]);
                sc[0][mt] = mfma16(ak1, qf[0][1], sc[0][mt]);
                sc[1][mt] = mfma16(ak0, qf[1][0], sc[1][mt]);
                sc[1][mt] = mfma16(ak1, qf[1][1], sc[1][mt]);
            }

            // mask + bias + online-softmax update (per-lane state, query = l16)
            float al[2];
#pragma unroll
            for (int nt = 0; nt < 2; ++nt) {
                const int qi = qw0 + nt * 16 + l16;
                const int db = qi - ks0 - q4 * 4;  // delta = db - mt*16 - r
                float tmx = -1e30f;
#pragma unroll
                for (int mt = 0; mt < 4; ++mt)
#pragma unroll
                    for (int r = 0; r < 4; ++r) {
                        int delta = db - mt * 16 - r;
                        float v = sc[nt][mt][r] * scale2 + slope2 * (float)delta;
                        v = ((unsigned)delta <= 512u) ? v : -1e30f;
                        sc[nt][mt][r] = v;
                        tmx = fmaxf(tmx, v);
                    }
                tmx = fmaxf(tmx, __shfl_xor(tmx, 16));
                tmx = fmaxf(tmx, __shfl_xor(tmx, 32));
                float mnew = fmaxf(mrow[nt], tmx);
                al[nt] = exp2f(mrow[nt] - mnew);
                mrow[nt] = mnew;
#pragma unroll
                for (int mtd = 0; mtd < 4; ++mtd)
                    O[mtd][nt] *= al[nt];
            }

            // P (packed b64 writes into own 32-row strip) + row-sum
            float rsum[2] = {0.0f, 0.0f};
#pragma unroll
            for (int nt = 0; nt < 2; ++nt) {
                int qrow = w * 32 + nt * 16 + l16;
#pragma unroll
                for (int mt = 0; mt < 4; ++mt) {
                    float p0 = exp2f(sc[nt][mt][0] - mrow[nt]);
                    float p1 = exp2f(sc[nt][mt][1] - mrow[nt]);
                    float p2 = exp2f(sc[nt][mt][2] - mrow[nt]);
                    float p3 = exp2f(sc[nt][mt][3] - mrow[nt]);
                    rsum[nt] += (p0 + p1) + (p2 + p3);
                    uint2 pk;
                    pk.x = pkbf(p0, p1);
                    pk.y = pkbf(p2, p3);
                    *(uint2*)&Ps[qrow * 72 + mt * 16 + q4 * 4] = pk;
                }
            }

            // PV: A = V^T (swizzled VTs), B = P^T (same-wave Ps strip; in-order DS)
#pragma unroll
            for (int kt = 0; kt < 2; ++kt) {
                bf16x8 bp0 = *(const bf16x8*)&Ps[(w * 32 + l16) * 72 + kt * 32 + q4 * 8];
                bf16x8 bp1 = *(const bf16x8*)&Ps[(w * 32 + 16 + l16) * 72 + kt * 32 + q4 * 8];
#pragma unroll
                for (int mtd = 0; mtd < 4; ++mtd) {
                    int d = mtd * 16 + l16;
                    bf16x8 av = *(const bf16x8*)&VTs[d * 128 +
                        ((hh * 8 + ((kt * 4 + q4) ^ (l16 & 7))) << 3)];
                    O[mtd][0] = mfma16(av, bp0, O[mtd][0]);
                    O[mtd][1] = mfma16(av, bp1, O[mtd][1]);
                }
            }
#pragma unroll
            for (int nt = 0; nt < 2; ++nt) {
                float rs = rsum[nt];
                rs += __shfl_xor(rs, 16);
                rs += __shfl_xor(rs, 32);
                lrow[nt] = lrow[nt] * al[nt] + rs;
            }
        }

        __syncthreads();  // all waves done reading Ks/VTs
        if (ki + 1 < nkt) {
#pragma unroll
            for (int p = 0; p < 4; ++p) {
                *(uint4*)&Ks[(p * 32 + srow) * 64 + ksoff] = kpre[p];
                int d = w * 16 + p * 4 + vr;
                *(uint4*)&VTs[d * 128 + vs * 8] = vpre[p];
            }
        }
        __syncthreads();  // commits visible
    }

    // epilogue: normalize, transpose O^T -> O via swizzled Ot (aliases Ks;
    // per-wave 32-query strips -> same-wave DS ordering, no barrier needed)
#pragma unroll
    for (int nt = 0; nt < 2; ++nt) {
        float inv = (lrow[nt] > 0.0f) ? 1.0f / lrow[nt] : 0.0f;
        int qrow = w * 32 + nt * 16 + l16;
#pragma unroll
        for (int mtd = 0; mtd < 4; ++mtd) {
            int chunk = (mtd * 2 + (q4 >> 1)) ^ (l16 & 7);
            uint2 pk;
            pk.x = pkbf(O[mtd][nt][0] * inv, O[mtd][nt][1] * inv);
            pk.y = pkbf(O[mtd][nt][2] * inv, O[mtd][nt][3] * inv);
            *(uint2*)&Ot[qrow * 64 + (chunk << 3) + (q4 & 1) * 4] = pk;
        }
    }
    const size_t obase = ((size_t)b * 2048 + q0) * 1024 + (size_t)h * 64;
#pragma unroll
    for (int i = 0; i < 4; ++i) {
        int u = i * 64 + lane;
        int row = u >> 3, ch = u & 7;
        int q = w * 32 + row;
        *(uint4*)&o[obase + (size_t)q * 1024 + ch * 8] =
            *(const uint4*)&Ot[q * 64 + ((ch ^ (row & 7)) << 3)];
    }
}

extern "C" void kernel_launch(void* const* d_in, const int* in_sizes, int n_in,
                              void* d_out, int out_size, void* d_ws, size_t ws_size,
                              hipStream_t stream) {
    char* ws = (char*)d_ws;
    int* flag = (int*)ws;
    size_t off = 256;
    __bf16* xb  = (__bf16*)(ws + off); off += (size_t)8192 * 1024 * 2;
    __bf16* wib = (__bf16*)(ws + off); off += (size_t)3072 * 1024 * 2;
    __bf16* wob = (__bf16*)(ws + off); off += (size_t)1024 * 1024 * 2;
    __bf16* qk  = (__bf16*)(ws + off); off += (size_t)8192 * 2048 * 2;
    __bf16* vT  = (__bf16*)(ws + off); off += (size_t)4 * 16 * 64 * 2048 * 2;
    __bf16* o   = (__bf16*)(ws + off);

    init_flag<<<1, 1, 0, stream>>>(flag);
    int nscan = in_sizes[2] < 65536 ? in_sizes[2] : 65536;
    detect_f32<<<16, 256, 0, stream>>>((const unsigned short*)d_in[2], nscan, flag);
    cvt_all<<<1024, 256, 0, stream>>>(d_in[0], d_in[1], d_in[2], xb, wib, wob, flag);

    // qkv projection: Q,K -> qk (pitch 2048); V -> vT transposed
    gemm_bt<<<dim3(24, 64), 256, 0, stream>>>(d_in[0], xb, d_in[1], wib,
                                              qk, nullptr, vT, flag,
                                              8192, 3072, 1024, 2048);
    // attention
    attn<<<dim3(16, 16, 4), 256, 0, stream>>>(qk, vT, o);
    // out = o @ w_out^T (output dtype per flag)
    gemm_bt<<<dim3(8, 64), 256, 0, stream>>>(o, o, d_in[2], wob,
                                             (__bf16*)d_out, (float*)d_out,
                                             nullptr, flag,
                                             8192, 1024, 1024, 1024);
}